// Round 2
// baseline (105131.372 us; speedup 1.0000x reference)
//
#include <hip/hip_runtime.h>
#include <cmath>

#define Hdim 768
#define Bb 32
#define Kb 5
#define Ss 64
#define Vv 30522
#define Tt 40
#define SEPTOK 102

// ---------------------------------------------------------------------------
// Generic GEMM with fp64 accumulation: out[n,i] = f32(acc) (+ bias[i], f32 add)
// acc = sum_p X[n*xrs+p] * W[i*P+p] in double (true value, order-noise-free).
// P must be a multiple of 256; N a multiple of NT.
// ---------------------------------------------------------------------------
template<int NT>
__global__ __launch_bounds__(256) void gemm_k(int N, int P, int I, int xrs,
    const float* __restrict__ X, const float* __restrict__ W,
    const float* __restrict__ bias, float* __restrict__ out)
{
    __shared__ __align__(16) float xs[NT][256];
    int i  = blockIdx.x * 256 + threadIdx.x;
    int n0 = blockIdx.y * NT;
    double acc[NT];
#pragma unroll
    for (int r = 0; r < NT; r++) acc[r] = 0.0;
    int nch = P >> 8;
    for (int c = 0; c < nch; c++) {
        __syncthreads();
#pragma unroll
        for (int r = 0; r < NT; r++)
            xs[r][threadIdx.x] = X[(size_t)(n0 + r) * xrs + c * 256 + threadIdx.x];
        __syncthreads();
        if (i < I) {
            const float4* w4 = reinterpret_cast<const float4*>(W + (size_t)i * P + c * 256);
            for (int p4 = 0; p4 < 64; p4++) {
                float4 w = w4[p4];
                double wx = (double)w.x, wy = (double)w.y, wz = (double)w.z, ww = (double)w.w;
#pragma unroll
                for (int r = 0; r < NT; r++) {
                    float4 xv = *reinterpret_cast<const float4*>(&xs[r][p4 * 4]);
                    acc[r] = fma((double)xv.x, wx, acc[r]);
                    acc[r] = fma((double)xv.y, wy, acc[r]);
                    acc[r] = fma((double)xv.z, wz, acc[r]);
                    acc[r] = fma((double)xv.w, ww, acc[r]);
                }
            }
        }
    }
    if (i < I) {
#pragma unroll
        for (int r = 0; r < NT; r++) {
            float s = (float)acc[r];                       // round matmul to f32
            if (bias) s = __fadd_rn(s, bias[i]);           // then f32 bias add (as ref)
            out[(size_t)(n0 + r) * I + i] = s;
        }
    }
}

__global__ void transpose_k(const float* __restrict__ in, float* __restrict__ out) {
    int idx = blockIdx.x * 256 + threadIdx.x;  // H*H
    if (idx >= Hdim * Hdim) return;
    int i = idx / Hdim, j = idx - i * Hdim;
    out[(size_t)j * Hdim + i] = in[idx];
}

// gather parent hidden + token embedding into per-step buffers
__global__ __launch_bounds__(256) void gather_k(int N, int Kcur,
    const int* __restrict__ maps, const int* __restrict__ toks,
    const float* __restrict__ h_beam, const float* __restrict__ E,
    float* __restrict__ h_g, float* __restrict__ xbuf)
{
    int n = blockIdx.x;
    if (n >= N) return;
    int b = n / Kcur;
    int tok = toks ? toks[n] : SEPTOK;
    const float* er = E + (size_t)tok * Hdim;
    if (maps) {
        const float* hs = h_beam + (size_t)(b * Kb + maps[n]) * Hdim;
        for (int j = threadIdx.x; j < Hdim; j += 256) {
            h_g[(size_t)n * Hdim + j]  = hs[j];
            xbuf[(size_t)n * 1536 + j] = er[j];
        }
    } else {  // step 0: zero hidden
        for (int j = threadIdx.x; j < Hdim; j += 256) {
            h_g[(size_t)n * Hdim + j]  = 0.f;
            xbuf[(size_t)n * 1536 + j] = er[j];
        }
    }
}

// step-0 broadcast: h_beam[b,k,:] = h_tmp[b,:] for all k (ref broadcast_to)
__global__ __launch_bounds__(256) void bcast_k(const float* __restrict__ h_tmp,
                                               float* __restrict__ h_beam)
{
    int b = blockIdx.x;
    for (int j = threadIdx.x; j < Hdim; j += 256) {
        float v = h_tmp[(size_t)b * Hdim + j];
        for (int k = 0; k < Kb; k++)
            h_beam[(size_t)(b * Kb + k) * Hdim + j] = v;
    }
}

// attention: e = tanh(srcWa + hUa) @ va; softmax over S; ctx -> xbuf[768:]
__global__ __launch_bounds__(256) void attn2_k(int N, int Kcur,
    const float* __restrict__ hUa, const float* __restrict__ srcWa,
    const float* __restrict__ src, const float* __restrict__ va,
    float* __restrict__ xbuf)
{
    __shared__ float hu[Hdim];
    __shared__ float va_s[Hdim];
    __shared__ float e_s[Ss];
    __shared__ float a_s[Ss];
    int n = blockIdx.x, tid = threadIdx.x;
    if (n >= N) return;
    int b = n / Kcur;
    for (int j = tid; j < Hdim; j += 256) {
        hu[j]   = hUa[(size_t)n * Hdim + j];
        va_s[j] = va[j];
    }
    __syncthreads();
    int wv = tid >> 6, ln = tid & 63;
    for (int s = wv * 16; s < wv * 16 + 16; s++) {
        const float* sw = srcWa + (size_t)(b * Ss + s) * Hdim;
        double p = 0.0;
        for (int j = ln; j < Hdim; j += 64) {
            float tv = (float)tanh((double)__fadd_rn(sw[j], hu[j]));  // f32 add, true tanh
            p = fma((double)tv, (double)va_s[j], p);
        }
        for (int off = 32; off; off >>= 1) p += __shfl_down(p, off, 64);
        if (ln == 0) e_s[s] = (float)p;
    }
    __syncthreads();
    if (tid < 64) {
        float v = e_s[tid], m = v;
        for (int off = 32; off; off >>= 1) m = fmaxf(m, __shfl_xor(m, off, 64));
        float p = (float)exp((double)__fsub_rn(v, m));
        double sum = (double)p;
        for (int off = 32; off; off >>= 1) sum += __shfl_xor(sum, off, 64);
        a_s[tid] = __fdiv_rn(p, (float)sum);
    }
    __syncthreads();
    for (int j = tid; j < Hdim; j += 256) {
        double acc = 0.0;
        for (int s = 0; s < Ss; s++)
            acc = fma((double)a_s[s], (double)src[(size_t)(b * Ss + s) * Hdim + j], acc);
        xbuf[(size_t)n * 1536 + 768 + j] = (float)acc;
    }
}

// GRU gates, transcendentals in double rounded to f32, f32 combine chain as ref
__global__ __launch_bounds__(256) void gate_k(int N,
    const float* __restrict__ gx, const float* __restrict__ gh,
    const float* __restrict__ h_g, float* __restrict__ h_out)
{
    int idx = blockIdx.x * 256 + threadIdx.x;
    if (idx >= N * Hdim) return;
    int n = idx / Hdim, i = idx - n * Hdim;
    const float* gxr = gx + (size_t)n * 2304;
    const float* ghr = gh + (size_t)n * 2304;
    float xr = gxr[i], xz = gxr[768 + i], xn = gxr[1536 + i];
    float hr = ghr[i], hz = ghr[768 + i], hn = ghr[1536 + i];
    float r  = (float)(1.0 / (1.0 + exp(-(double)__fadd_rn(xr, hr))));
    float z  = (float)(1.0 / (1.0 + exp(-(double)__fadd_rn(xz, hz))));
    float nn = (float)tanh((double)__fadd_rn(xn, __fmul_rn(r, hn)));
    float hv = h_g[(size_t)n * Hdim + i];
    float h2 = __fadd_rn(__fmul_rn(__fsub_rn(1.f, z), nn), __fmul_rn(z, hv));
    h_out[(size_t)n * Hdim + i] = h2;
}

// per-row max (exact) and l = f32(log(f32(sum exp))) with fp64 summation of
// f32-rounded exp terms (matches ref termwise, removes order noise)
__global__ __launch_bounds__(256) void lse_k(int N,
    const float* __restrict__ logits, float* __restrict__ mx, float* __restrict__ lgs)
{
    __shared__ float  redf[256];
    __shared__ double redd[256];
    int n = blockIdx.x, tid = threadIdx.x;
    const float* lg = logits + (size_t)n * Vv;
    float m = -INFINITY;
    for (int v = tid; v < Vv; v += 256) m = fmaxf(m, lg[v]);
    redf[tid] = m; __syncthreads();
    for (int off = 128; off; off >>= 1) {
        if (tid < off) redf[tid] = fmaxf(redf[tid], redf[tid + off]);
        __syncthreads();
    }
    m = redf[0];
    double s = 0.0;
    for (int v = tid; v < Vv; v += 256) {
        float ex = (float)exp((double)__fsub_rn(lg[v], m));
        s += (double)ex;
    }
    redd[tid] = s; __syncthreads();
    for (int off = 128; off; off >>= 1) {
        if (tid < off) redd[tid] += redd[tid + off];
        __syncthreads();
    }
    if (tid == 0) {
        mx[n] = m;
        float sf = (float)redd[0];
        lgs[n] = (float)log((double)sf);
    }
}

// ---------------------------------------------------------------------------
// Unified top-5 via 5 passes of global argmax with exclusion. Order-independent
// (unique lexicographic max per pass), tie-break = lowest flat index, exactly
// jax.lax.top_k semantics. t==0: range V, score 0, den 1, all-active.
// ---------------------------------------------------------------------------
__global__ __launch_bounds__(256) void topk5_k(int t,
    const float* __restrict__ logits, const float* __restrict__ mx, const float* __restrict__ lgs,
    float* scores, float* ended, float* lengths,
    int* toks_cur, int* maps_cur, int* toks_all, int* maps_all)
{
    __shared__ float sc_s[Kb], den_s[Kb], end_s[Kb], len_s[Kb], mx_s[Kb], lg_s[Kb];
    __shared__ int   selj[Kb];
    __shared__ float red_v[256];
    __shared__ int   red_j[256];
    int b = blockIdx.x, tid = threadIdx.x;
    int Kcur = (t == 0) ? 1 : Kb;
    if (tid < Kb) {
        if (t == 0) {
            sc_s[tid] = 0.f; end_s[tid] = 0.f; len_s[tid] = 0.f; den_s[tid] = 1.f;
            mx_s[tid] = mx[b]; lg_s[tid] = lgs[b];
        } else {
            float e0 = ended[b * Kb + tid];
            float ln = __fadd_rn(lengths[b * Kb + tid], (e0 == 0.f) ? 1.f : 0.f);
            sc_s[tid]  = scores[b * Kb + tid];
            end_s[tid] = e0;
            len_s[tid] = ln;
            den_s[tid] = (tid < Kb - 1) ? (float)pow((double)ln, (double)0.7f) : 1.f;
            mx_s[tid]  = mx[b * Kb + tid];
            lg_s[tid]  = lgs[b * Kb + tid];
        }
    }
    __syncthreads();
    int range = Kcur * Vv;
    const float* lbase = logits + (size_t)b * Kcur * Vv;
    for (int pass = 0; pass < Kb; pass++) {
        float bv = -INFINITY; int bj = 0x7fffffff;
        int k = 0, v = tid;  // incremental j -> (k, v) decomposition
        for (int j = tid; j < range; j += 256) {
            bool skip = false;
            for (int q = 0; q < pass; q++) skip |= (selj[q] == j);
            if (!skip) {
                float lp;
                if (end_s[k] == 0.f)
                    lp = __fsub_rn(__fsub_rn(lbase[(size_t)k * Vv + v], mx_s[k]), lg_s[k]);
                else
                    lp = (v == SEPTOK) ? 0.f : -1e9f;
                float val = __fdiv_rn(__fadd_rn(lp, sc_s[k]), den_s[k]);
                if (val > bv || (val == bv && j < bj)) { bv = val; bj = j; }
            }
            v += 256;
            if (v >= Vv) { v -= Vv; k++; }
        }
        red_v[tid] = bv; red_j[tid] = bj;
        __syncthreads();
        for (int off = 128; off; off >>= 1) {
            if (tid < off) {
                float ov = red_v[tid + off]; int oj = red_j[tid + off];
                if (ov > red_v[tid] || (ov == red_v[tid] && oj < red_j[tid])) {
                    red_v[tid] = ov; red_j[tid] = oj;
                }
            }
            __syncthreads();
        }
        if (tid == 0) selj[pass] = red_j[0];
        __syncthreads();
    }
    if (tid == 0) {
        for (int q = 0; q < Kb; q++) {
            int jj = selj[q];
            int pk = jj / Vv, vv = jj - pk * Vv;
            float lp;
            if (end_s[pk] == 0.f)
                lp = __fsub_rn(__fsub_rn(lbase[(size_t)pk * Vv + vv], mx_s[pk]), lg_s[pk]);
            else
                lp = (vv == SEPTOK) ? 0.f : -1e9f;
            float cand = __fadd_rn(lp, sc_s[pk]);      // unnormalized, as ref carries
            scores[b * Kb + q]   = cand;
            toks_cur[b * Kb + q] = vv;
            maps_cur[b * Kb + q] = (t == 0) ? 0 : pk;
            if (t == 0) {
                ended[b * Kb + q]   = 0.f;             // ref carry0: zeros regardless of SEP
                lengths[b * Kb + q] = 0.f;
            } else {
                // reference quirk: ended/lengths indexed by NEW slot, OLD meaning
                ended[b * Kb + q]   = (vv == SEPTOK) ? 1.f : end_s[q];
                lengths[b * Kb + q] = len_s[q];
            }
            toks_all[(size_t)t * Bb * Kb + b * Kb + q] = vv;
            maps_all[(size_t)t * Bb * Kb + b * Kb + q] = (t == 0) ? 0 : pk;
        }
    }
}

__global__ void back_k(const float* __restrict__ scores,
                       const int* __restrict__ toks_all, const int* __restrict__ maps_all,
                       int* __restrict__ out)
{
    int b = threadIdx.x;
    if (b >= Bb) return;
    int best = 0; float bvv = scores[b * Kb];
    for (int k = 1; k < Kb; k++) {
        float v = scores[b * Kb + k];
        if (v > bvv) { bvv = v; best = k; }  // strict > = first-occurrence argmax
    }
    int cur = best;
    for (int t = Tt - 1; t >= 0; t--) {
        out[b * Tt + t] = toks_all[t * Bb * Kb + b * Kb + cur];
        cur = maps_all[t * Bb * Kb + b * Kb + cur];
    }
}

// ---------------------------------------------------------------------------
extern "C" void kernel_launch(void* const* d_in, const int* in_sizes, int n_in,
                              void* d_out, int out_size, void* d_ws, size_t ws_size,
                              hipStream_t stream)
{
    const float* src  = (const float*)d_in[0];
    const float* E    = (const float*)d_in[1];
    const float* Wa   = (const float*)d_in[2];
    const float* Ua   = (const float*)d_in[3];
    const float* va   = (const float*)d_in[4];
    const float* W_ih = (const float*)d_in[5];
    const float* W_hh = (const float*)d_in[6];
    const float* b_ih = (const float*)d_in[7];
    const float* b_hh = (const float*)d_in[8];
    const float* Wo   = (const float*)d_in[9];
    const float* bo   = (const float*)d_in[10];
    int* out = (int*)d_out;

    // workspace bump allocator (~36 MB total)
    char* w = (char*)d_ws;
    auto alloc = [&](size_t elems) -> float* {
        float* p = (float*)w;
        w += ((elems * 4 + 255) / 256) * 256;
        return p;
    };
    float* srcWa   = alloc((size_t)Bb * Ss * Hdim);
    float* WaT     = alloc((size_t)Hdim * Hdim);
    float* UaT     = alloc((size_t)Hdim * Hdim);
    float* h_beam  = alloc((size_t)Bb * Kb * Hdim);   // hiddens per (b,k)
    float* h_tmp   = alloc((size_t)Bb * Hdim);        // step-0 contiguous h
    float* h_g     = alloc((size_t)Bb * Kb * Hdim);   // gathered parent h
    float* hUa     = alloc((size_t)Bb * Kb * Hdim);
    float* xbuf    = alloc((size_t)Bb * Kb * 1536);
    float* gx      = alloc((size_t)Bb * Kb * 2304);
    float* gh      = alloc((size_t)Bb * Kb * 2304);
    float* logits  = alloc((size_t)Bb * Kb * Vv);
    float* mx      = alloc(Bb * Kb);
    float* lgs     = alloc(Bb * Kb);
    float* scores  = alloc(Bb * Kb);
    float* ended   = alloc(Bb * Kb);
    float* lengths = alloc(Bb * Kb);
    int* toks_cur = (int*)alloc(Bb * Kb);
    int* maps_cur = (int*)alloc(Bb * Kb);
    int* toks_all = (int*)alloc((size_t)Tt * Bb * Kb);
    int* maps_all = (int*)alloc((size_t)Tt * Bb * Kb);

    transpose_k<<<(Hdim * Hdim + 255) / 256, 256, 0, stream>>>(Wa, WaT);
    transpose_k<<<(Hdim * Hdim + 255) / 256, 256, 0, stream>>>(Ua, UaT);
    // srcWa = src @ Wa  (constant across steps)
    gemm_k<16><<<dim3(3, (Bb * Ss) / 16), 256, 0, stream>>>(
        Bb * Ss, Hdim, Hdim, Hdim, src, WaT, nullptr, srcWa);

    for (int t = 0; t < Tt; t++) {
        int N  = (t == 0) ? Bb : Bb * Kb;
        int Kc = (t == 0) ? 1 : Kb;
        const int* mp = (t == 0) ? nullptr : maps_cur;
        const int* tk = (t == 0) ? nullptr : toks_cur;
        float* h_cur = (t == 0) ? h_tmp : h_beam;

        gather_k<<<N, 256, 0, stream>>>(N, Kc, mp, tk, h_beam, E, h_g, xbuf);
        gemm_k<16><<<dim3(3, N / 16), 256, 0, stream>>>(
            N, Hdim, Hdim, Hdim, h_g, UaT, nullptr, hUa);           // h @ Ua
        attn2_k<<<N, 256, 0, stream>>>(N, Kc, hUa, srcWa, src, va, xbuf);
        gemm_k<16><<<dim3(9, N / 16), 256, 0, stream>>>(
            N, 1536, 2304, 1536, xbuf, W_ih, b_ih, gx);             // x @ W_ih.T
        gemm_k<16><<<dim3(9, N / 16), 256, 0, stream>>>(
            N, Hdim, 2304, Hdim, h_g, W_hh, b_hh, gh);              // h @ W_hh.T
        gate_k<<<(N * Hdim + 255) / 256, 256, 0, stream>>>(N, gx, gh, h_g, h_cur);
        if (t == 0)
            bcast_k<<<Bb, 256, 0, stream>>>(h_tmp, h_beam);         // ref broadcast_to
        gemm_k<16><<<dim3((Vv + 255) / 256, N / 16), 256, 0, stream>>>(
            N, Hdim, Vv, Hdim, h_cur, Wo, bo, logits);              // h2 @ Wo.T
        lse_k<<<N, 256, 0, stream>>>(N, logits, mx, lgs);
        topk5_k<<<Bb, 256, 0, stream>>>(t, logits, mx, lgs, scores, ended, lengths,
                                        toks_cur, maps_cur, toks_all, maps_all);
    }
    back_k<<<1, 64, 0, stream>>>(scores, toks_all, maps_all, out);
}

// Round 3
// 75633.875 us; speedup vs baseline: 1.3900x; 1.3900x over previous
//
#include <hip/hip_runtime.h>
#include <cmath>
#include <cfloat>

#define Hdim 768
#define Bb 32
#define Kb 5
#define Ss 64
#define Vv 30522
#define Tt 40
#define SEPTOK 102

// ---------------------------------------------------------------------------
// fp64-accumulate GEMM, restructured:
//   out[n,i] = f32( sum_p Xd[n*P+p] * (double)W[p*sWp + i*sWi] )  (+bias, f32)
// Xd is fp64 (pre-converted, tiny). X addresses are wave-uniform -> SMEM.
// W access coalesced when sWi==1 (pre-transposed weight). No LDS, no syncs.
// N must be a multiple of NT.
// ---------------------------------------------------------------------------
template<int NT>
__global__ __launch_bounds__(256) void gemm64_k(int N, int P, int I,
    long long sWp, long long sWi,
    const double* __restrict__ Xd, const float* __restrict__ W,
    const float* __restrict__ bias, float* __restrict__ out)
{
    int i  = blockIdx.x * 256 + threadIdx.x;
    int ic = (i < I) ? i : (I - 1);           // clamp: keep control flow uniform
    int n0 = blockIdx.y * NT;
    const double* __restrict__ xrow = Xd + (size_t)n0 * P;
    const float*  __restrict__ wp   = W + (size_t)ic * sWi;
    double acc[NT];
#pragma unroll
    for (int r = 0; r < NT; r++) acc[r] = 0.0;
    for (int p = 0; p < P; p++) {
        double w = (double)(*wp);
        wp += sWp;
#pragma unroll
        for (int r = 0; r < NT; r++)
            acc[r] = ::fma(xrow[(size_t)r * P + p], w, acc[r]);
    }
    if (i < I) {
#pragma unroll
        for (int r = 0; r < NT; r++) {
            float s = (float)acc[r];                 // round true sum to f32
            if (bias) s = __fadd_rn(s, bias[ic]);    // then f32 bias add (as ref)
            out[(size_t)(n0 + r) * I + i] = s;
        }
    }
}

// tiled transpose: out[c*R + r] = in[r*C + c], coalesced both sides
__global__ __launch_bounds__(256) void transpose_tiled_k(
    const float* __restrict__ in, float* __restrict__ out, int R, int C)
{
    __shared__ float tile[32][33];
    int c0 = blockIdx.x * 32, r0 = blockIdx.y * 32;
    int tx = threadIdx.x & 31, ty = threadIdx.x >> 5;   // ty in [0,8)
    for (int dy = 0; dy < 32; dy += 8) {
        int r = r0 + ty + dy, c = c0 + tx;
        if (r < R && c < C) tile[ty + dy][tx] = in[(size_t)r * C + c];
    }
    __syncthreads();
    for (int dy = 0; dy < 32; dy += 8) {
        int r = r0 + tx, c = c0 + ty + dy;
        if (r < R && c < C) out[(size_t)c * R + r] = tile[tx][ty + dy];
    }
}

__global__ void cvt64_k(const float* __restrict__ in, double* __restrict__ out, int n) {
    int i = blockIdx.x * 256 + threadIdx.x;
    if (i < n) out[i] = (double)in[i];
}

// gather parent hidden + token embedding into fp64 per-step buffers
__global__ __launch_bounds__(256) void gather_k(int N, int Kcur,
    const int* __restrict__ maps, const int* __restrict__ toks,
    const float* __restrict__ h_beam, const float* __restrict__ E,
    double* __restrict__ h_gd, double* __restrict__ xbufd)
{
    int n = blockIdx.x;
    if (n >= N) return;
    int b = n / Kcur;
    int tok = toks ? toks[n] : SEPTOK;
    const float* er = E + (size_t)tok * Hdim;
    if (maps) {
        const float* hs = h_beam + (size_t)(b * Kb + maps[n]) * Hdim;
        for (int j = threadIdx.x; j < Hdim; j += 256) {
            h_gd[(size_t)n * Hdim + j]  = (double)hs[j];
            xbufd[(size_t)n * 1536 + j] = (double)er[j];
        }
    } else {  // step 0: zero hidden
        for (int j = threadIdx.x; j < Hdim; j += 256) {
            h_gd[(size_t)n * Hdim + j]  = 0.0;
            xbufd[(size_t)n * 1536 + j] = (double)er[j];
        }
    }
}

// step-0 broadcast: h_beam[b,k,:] = h_tmp[b,:]
__global__ __launch_bounds__(256) void bcast_k(const float* __restrict__ h_tmp,
                                               float* __restrict__ h_beam)
{
    int b = blockIdx.x;
    for (int j = threadIdx.x; j < Hdim; j += 256) {
        float v = h_tmp[(size_t)b * Hdim + j];
        for (int k = 0; k < Kb; k++)
            h_beam[(size_t)(b * Kb + k) * Hdim + j] = v;
    }
}

// attention: e = tanh(srcWa + hUa) @ va; softmax over S; ctx -> xbufd[768:]
__global__ __launch_bounds__(256) void attn2_k(int N, int Kcur,
    const float* __restrict__ hUa, const float* __restrict__ srcWa,
    const float* __restrict__ src, const float* __restrict__ va,
    double* __restrict__ xbufd)
{
    __shared__ float hu[Hdim];
    __shared__ float va_s[Hdim];
    __shared__ float e_s[Ss];
    __shared__ float a_s[Ss];
    int n = blockIdx.x, tid = threadIdx.x;
    if (n >= N) return;
    int b = n / Kcur;
    for (int j = tid; j < Hdim; j += 256) {
        hu[j]   = hUa[(size_t)n * Hdim + j];
        va_s[j] = va[j];
    }
    __syncthreads();
    int wv = tid >> 6, ln = tid & 63;
    for (int s = wv * 16; s < wv * 16 + 16; s++) {
        const float* sw = srcWa + (size_t)(b * Ss + s) * Hdim;
        double p = 0.0;
        for (int j = ln; j < Hdim; j += 64) {
            float tv = (float)tanh((double)__fadd_rn(sw[j], hu[j]));  // f32 add, true tanh
            p = ::fma((double)tv, (double)va_s[j], p);
        }
        for (int off = 32; off; off >>= 1) p += __shfl_down(p, off, 64);
        if (ln == 0) e_s[s] = (float)p;
    }
    __syncthreads();
    if (tid < 64) {
        float v = e_s[tid], m = v;
        for (int off = 32; off; off >>= 1) m = fmaxf(m, __shfl_xor(m, off, 64));
        float p = (float)exp((double)__fsub_rn(v, m));
        double sum = (double)p;
        for (int off = 32; off; off >>= 1) sum += __shfl_xor(sum, off, 64);
        a_s[tid] = __fdiv_rn(p, (float)sum);
    }
    __syncthreads();
    for (int j = tid; j < Hdim; j += 256) {
        double acc = 0.0;
        for (int s = 0; s < Ss; s++)
            acc = ::fma((double)a_s[s], (double)src[(size_t)(b * Ss + s) * Hdim + j], acc);
        xbufd[(size_t)n * 1536 + 768 + j] = (double)(float)acc;  // round to f32 (ref x is f32)
    }
}

// GRU gates; writes f32 hidden state + fp64 copy for the logits GEMM
__global__ __launch_bounds__(256) void gate_k(int N,
    const float* __restrict__ gx, const float* __restrict__ gh,
    const double* __restrict__ h_gd, float* __restrict__ h_out,
    double* __restrict__ h2d)
{
    int idx = blockIdx.x * 256 + threadIdx.x;
    if (idx >= N * Hdim) return;
    int n = idx / Hdim, i = idx - n * Hdim;
    const float* gxr = gx + (size_t)n * 2304;
    const float* ghr = gh + (size_t)n * 2304;
    float xr = gxr[i], xz = gxr[768 + i], xn = gxr[1536 + i];
    float hr = ghr[i], hz = ghr[768 + i], hn = ghr[1536 + i];
    float r  = (float)(1.0 / (1.0 + exp(-(double)__fadd_rn(xr, hr))));
    float z  = (float)(1.0 / (1.0 + exp(-(double)__fadd_rn(xz, hz))));
    float nn = (float)tanh((double)__fadd_rn(xn, __fmul_rn(r, hn)));
    float hv = (float)h_gd[(size_t)n * Hdim + i];
    float h2 = __fadd_rn(__fmul_rn(__fsub_rn(1.f, z), nn), __fmul_rn(z, hv));
    h_out[(size_t)n * Hdim + i] = h2;
    h2d[(size_t)n * Hdim + i]   = (double)h2;
}

// per-row max and l = f32(log(f32(sum of f32-rounded exp)))
__global__ __launch_bounds__(256) void lse_k(int N,
    const float* __restrict__ logits, float* __restrict__ mx, float* __restrict__ lgs)
{
    __shared__ float  redf[256];
    __shared__ double redd[256];
    int n = blockIdx.x, tid = threadIdx.x;
    const float* lg = logits + (size_t)n * Vv;
    float m = -INFINITY;
    for (int v = tid; v < Vv; v += 256) m = fmaxf(m, lg[v]);
    redf[tid] = m; __syncthreads();
    for (int off = 128; off; off >>= 1) {
        if (tid < off) redf[tid] = fmaxf(redf[tid], redf[tid + off]);
        __syncthreads();
    }
    m = redf[0];
    double s = 0.0;
    for (int v = tid; v < Vv; v += 256) {
        float ex = (float)exp((double)__fsub_rn(lg[v], m));
        s += (double)ex;
    }
    redd[tid] = s; __syncthreads();
    for (int off = 128; off; off >>= 1) {
        if (tid < off) redd[tid] += redd[tid + off];
        __syncthreads();
    }
    if (tid == 0) {
        mx[n] = m;
        float sf = (float)redd[0];
        lgs[n] = (float)log((double)sf);
    }
}

// ------------------------- top-k helpers -----------------------------------
__device__ __forceinline__ bool betterf(float va, int ja, float vb, int jb) {
    return (va > vb) || (va == vb && ja < jb);  // jax tie-break: lower index
}
__device__ __forceinline__ void ins5(float* tv, int* tj, float v, int j) {
    if (!betterf(v, j, tv[4], tj[4])) return;
    tv[4] = v; tj[4] = j;
#pragma unroll
    for (int q = 4; q > 0; q--) {
        if (betterf(tv[q], tj[q], tv[q - 1], tj[q - 1])) {
            float t = tv[q]; tv[q] = tv[q - 1]; tv[q - 1] = t;
            int  ti = tj[q]; tj[q] = tj[q - 1]; tj[q - 1] = ti;
        }
    }
}

// single scan with per-thread top-5, then 5-pass argmax over the 1280-entry
// LDS pool (order-independent; (val, flat-idx) lexicographic = jax top_k).
// Ended beams contribute exactly one analytic candidate (SEP); their other
// candidates (~ -1e9/den) can never reach the top-5.
__global__ __launch_bounds__(256) void topk5_k(int t,
    const float* __restrict__ logits, const float* __restrict__ mx, const float* __restrict__ lgs,
    float* scores, float* ended, float* lengths,
    int* toks_cur, int* maps_cur, int* toks_all, int* maps_all)
{
    __shared__ float sc_s[Kb], den_s[Kb], end_s[Kb], len_s[Kb], mx_s[Kb], lg_s[Kb];
    __shared__ float mv[256 * 5];
    __shared__ int   mj[256 * 5];
    __shared__ float rv[256];
    __shared__ int   rj[256];
    __shared__ int   selj[Kb];
    int b = blockIdx.x, tid = threadIdx.x;
    int Kcur = (t == 0) ? 1 : Kb;
    if (tid < Kb) {
        if (t == 0) {
            sc_s[tid] = 0.f; end_s[tid] = 0.f; len_s[tid] = 0.f; den_s[tid] = 1.f;
            mx_s[tid] = mx[b]; lg_s[tid] = lgs[b];
        } else {
            float e0 = ended[b * Kb + tid];
            float ln = __fadd_rn(lengths[b * Kb + tid], (e0 == 0.f) ? 1.f : 0.f);
            sc_s[tid]  = scores[b * Kb + tid];
            end_s[tid] = e0;
            len_s[tid] = ln;
            den_s[tid] = (tid < Kb - 1) ? (float)pow((double)ln, (double)0.7f) : 1.f;
            mx_s[tid]  = mx[b * Kb + tid];
            lg_s[tid]  = lgs[b * Kb + tid];
        }
    }
    __syncthreads();
    const float* lbase = logits + (size_t)b * Kcur * Vv;
    float tv[5]; int tj[5];
#pragma unroll
    for (int q = 0; q < 5; q++) { tv[q] = -INFINITY; tj[q] = 0x7fffffff; }
    for (int k = 0; k < Kcur; k++) {
        if (end_s[k] == 0.f) {
            float m = mx_s[k], l = lg_s[k], sck = sc_s[k], den = den_s[k];
            const float* lg = lbase + (size_t)k * Vv;
            for (int v = tid; v < Vv; v += 256) {
                float lp  = __fsub_rn(__fsub_rn(lg[v], m), l);
                float val = __fdiv_rn(__fadd_rn(lp, sck), den);
                ins5(tv, tj, val, k * Vv + v);
            }
        } else if (tid == 0) {
            // lp at SEP is 0: val = fdiv(fadd(0, sc), den) == fdiv(sc, den)
            float val = __fdiv_rn(sc_s[k], den_s[k]);
            ins5(tv, tj, val, k * Vv + SEPTOK);
        }
    }
#pragma unroll
    for (int q = 0; q < 5; q++) { mv[tid * 5 + q] = tv[q]; mj[tid * 5 + q] = tj[q]; }
    __syncthreads();
    for (int pass = 0; pass < Kb; pass++) {
        float bv = -INFINITY; int bj = 0x7fffffff;
#pragma unroll
        for (int q = 0; q < 5; q++) {
            float v = mv[tid * 5 + q]; int j = mj[tid * 5 + q];
            if (betterf(v, j, bv, bj)) { bv = v; bj = j; }
        }
        rv[tid] = bv; rj[tid] = bj;
        __syncthreads();
        for (int off = 128; off; off >>= 1) {
            if (tid < off) {
                float ov = rv[tid + off]; int oj = rj[tid + off];
                if (betterf(ov, oj, rv[tid], rj[tid])) { rv[tid] = ov; rj[tid] = oj; }
            }
            __syncthreads();
        }
        if (tid == 0) selj[pass] = rj[0];
        __syncthreads();
#pragma unroll
        for (int q = 0; q < 5; q++)                      // invalidate selected (j unique)
            if (mj[tid * 5 + q] == selj[pass]) { mv[tid * 5 + q] = -INFINITY; mj[tid * 5 + q] = 0x7fffffff; }
        __syncthreads();
    }
    if (tid == 0) {
        for (int q = 0; q < Kb; q++) {
            int jj = selj[q];
            int pk = jj / Vv, vv = jj - pk * Vv;
            float lp;
            if (end_s[pk] == 0.f)
                lp = __fsub_rn(__fsub_rn(lbase[(size_t)pk * Vv + vv], mx_s[pk]), lg_s[pk]);
            else
                lp = (vv == SEPTOK) ? 0.f : -1e9f;
            float cand = __fadd_rn(lp, sc_s[pk]);        // unnormalized, as ref carries
            scores[b * Kb + q]   = cand;
            toks_cur[b * Kb + q] = vv;
            maps_cur[b * Kb + q] = (t == 0) ? 0 : pk;
            if (t == 0) {
                ended[b * Kb + q]   = 0.f;
                lengths[b * Kb + q] = 0.f;
            } else {
                // reference quirk: ended/lengths indexed by NEW slot, OLD meaning
                ended[b * Kb + q]   = (vv == SEPTOK) ? 1.f : end_s[q];
                lengths[b * Kb + q] = len_s[q];
            }
            toks_all[(size_t)t * Bb * Kb + b * Kb + q] = vv;
            maps_all[(size_t)t * Bb * Kb + b * Kb + q] = (t == 0) ? 0 : pk;
        }
    }
}

__global__ void back_k(const float* __restrict__ scores,
                       const int* __restrict__ toks_all, const int* __restrict__ maps_all,
                       int* __restrict__ out)
{
    int b = threadIdx.x;
    if (b >= Bb) return;
    int best = 0; float bvv = scores[b * Kb];
    for (int k = 1; k < Kb; k++) {
        float v = scores[b * Kb + k];
        if (v > bvv) { bvv = v; best = k; }  // strict > = first-occurrence argmax
    }
    int cur = best;
    for (int t = Tt - 1; t >= 0; t--) {
        out[b * Tt + t] = toks_all[t * Bb * Kb + b * Kb + cur];
        cur = maps_all[t * Bb * Kb + b * Kb + cur];
    }
}

// ---------------------------------------------------------------------------
extern "C" void kernel_launch(void* const* d_in, const int* in_sizes, int n_in,
                              void* d_out, int out_size, void* d_ws, size_t ws_size,
                              hipStream_t stream)
{
    const float* src  = (const float*)d_in[0];
    const float* E    = (const float*)d_in[1];
    const float* Wa   = (const float*)d_in[2];
    const float* Ua   = (const float*)d_in[3];
    const float* va   = (const float*)d_in[4];
    const float* W_ih = (const float*)d_in[5];
    const float* W_hh = (const float*)d_in[6];
    const float* b_ih = (const float*)d_in[7];
    const float* b_hh = (const float*)d_in[8];
    const float* Wo   = (const float*)d_in[9];
    const float* bo   = (const float*)d_in[10];
    int* out = (int*)d_out;

    // workspace bump allocator
    char* w = (char*)d_ws;
    size_t used = 0;
    auto alloc = [&](size_t bytes) -> char* {
        char* p = w + used;
        used += (bytes + 255) & ~(size_t)255;
        return p;
    };
    // core buffers (~47 MB)
    float*  srcWa   = (float*) alloc((size_t)Bb * Ss * Hdim * 4);
    double* srcd    = (double*)alloc((size_t)Bb * Ss * Hdim * 8);
    float*  h_beam  = (float*) alloc((size_t)Bb * Kb * Hdim * 4);
    float*  h_tmp   = (float*) alloc((size_t)Bb * Hdim * 4);
    double* h_gd    = (double*)alloc((size_t)Bb * Kb * Hdim * 8);
    float*  hUa     = (float*) alloc((size_t)Bb * Kb * Hdim * 4);
    double* xbufd   = (double*)alloc((size_t)Bb * Kb * 1536 * 8);
    float*  gx      = (float*) alloc((size_t)Bb * Kb * 2304 * 4);
    float*  gh      = (float*) alloc((size_t)Bb * Kb * 2304 * 4);
    double* h2d     = (double*)alloc((size_t)Bb * Kb * Hdim * 8);
    float*  logits  = (float*) alloc((size_t)Bb * Kb * Vv * 4);
    float*  mx      = (float*) alloc(Bb * Kb * 4);
    float*  lgs     = (float*) alloc(Bb * Kb * 4);
    float*  scores  = (float*) alloc(Bb * Kb * 4);
    float*  ended   = (float*) alloc(Bb * Kb * 4);
    float*  lengths = (float*) alloc(Bb * Kb * 4);
    int* toks_cur = (int*)alloc(Bb * Kb * 4);
    int* maps_cur = (int*)alloc(Bb * Kb * 4);
    int* toks_all = (int*)alloc((size_t)Tt * Bb * Kb * 4);
    int* maps_all = (int*)alloc((size_t)Tt * Bb * Kb * 4);

    // layered fallback for weight transposes (coalesced W reads)
    size_t sz_ihT = (size_t)2304 * 1536 * 4;
    size_t sz_hhT = (size_t)2304 * Hdim * 4;
    size_t sz_woT = (size_t)Vv * Hdim * 4;
    float* wihT = nullptr; float* whhT = nullptr; float* woT = nullptr;
    if (ws_size >= used + sz_ihT + sz_hhT + 512) {
        wihT = (float*)alloc(sz_ihT);
        whhT = (float*)alloc(sz_hhT);
    }
    if (ws_size >= used + sz_woT + 512) {
        woT = (float*)alloc(sz_woT);
    }

    // ---------------- one-time init (inside capture; deterministic) --------
    cvt64_k<<<((Bb * Ss * Hdim) + 255) / 256, 256, 0, stream>>>(src, srcd, Bb * Ss * Hdim);
    if (wihT) {
        transpose_tiled_k<<<dim3((1536 + 31) / 32, (2304 + 31) / 32), 256, 0, stream>>>(W_ih, wihT, 2304, 1536);
        transpose_tiled_k<<<dim3((Hdim + 31) / 32, (2304 + 31) / 32), 256, 0, stream>>>(W_hh, whhT, 2304, Hdim);
    }
    if (woT)
        transpose_tiled_k<<<dim3((Hdim + 31) / 32, (Vv + 31) / 32), 256, 0, stream>>>(Wo, woT, Vv, Hdim);

    // srcWa = src @ Wa : W = Wa[p][i] row-major -> sWp=768, sWi=1 (coalesced)
    gemm64_k<8><<<dim3(3, (Bb * Ss) / 8), 256, 0, stream>>>(
        Bb * Ss, Hdim, Hdim, (long long)Hdim, 1LL, srcd, Wa, nullptr, srcWa);

    // weight access descriptors: {ptr, sWp, sWi}
    const float* Wih_p = wihT ? wihT : W_ih;
    long long    Wih_sp = wihT ? 2304LL : 1LL, Wih_si = wihT ? 1LL : 1536LL;
    const float* Whh_p = whhT ? whhT : W_hh;
    long long    Whh_sp = whhT ? 2304LL : 1LL, Whh_si = whhT ? 1LL : (long long)Hdim;
    const float* Wo_p  = woT ? woT : Wo;
    long long    Wo_sp = woT ? (long long)Vv : 1LL, Wo_si = woT ? 1LL : (long long)Hdim;

    for (int t = 0; t < Tt; t++) {
        int N  = (t == 0) ? Bb : Bb * Kb;
        int Kc = (t == 0) ? 1 : Kb;
        const int* mp = (t == 0) ? nullptr : maps_cur;
        const int* tk = (t == 0) ? nullptr : toks_cur;
        float* h_cur = (t == 0) ? h_tmp : h_beam;

        gather_k<<<N, 256, 0, stream>>>(N, Kc, mp, tk, h_beam, E, h_gd, xbufd);
        // h @ Ua : Ua[p][i] -> sWp=768, sWi=1
        gemm64_k<8><<<dim3(3, N / 8), 256, 0, stream>>>(
            N, Hdim, Hdim, (long long)Hdim, 1LL, h_gd, Ua, nullptr, hUa);
        attn2_k<<<N, 256, 0, stream>>>(N, Kc, hUa, srcWa, src, va, xbufd);
        // x @ W_ih.T
        gemm64_k<8><<<dim3(9, N / 8), 256, 0, stream>>>(
            N, 1536, 2304, Wih_sp, Wih_si, xbufd, Wih_p, b_ih, gx);
        // h @ W_hh.T
        gemm64_k<8><<<dim3(9, N / 8), 256, 0, stream>>>(
            N, Hdim, 2304, Whh_sp, Whh_si, h_gd, Whh_p, b_hh, gh);
        gate_k<<<(N * Hdim + 255) / 256, 256, 0, stream>>>(N, gx, gh, h_gd, h_cur, h2d);
        if (t == 0)
            bcast_k<<<Bb, 256, 0, stream>>>(h_tmp, h_beam);
        // h2 @ Wo.T  (the big one)
        gemm64_k<32><<<dim3((Vv + 255) / 256, N / 32), 256, 0, stream>>>(
            N, Hdim, Vv, Wo_sp, Wo_si, h2d, Wo_p, bo, logits);
        lse_k<<<N, 256, 0, stream>>>(N, logits, mx, lgs);
        topk5_k<<<Bb, 256, 0, stream>>>(t, logits, mx, lgs, scores, ended, lengths,
                                        toks_cur, maps_cur, toks_all, maps_all);
    }
    back_k<<<1, 64, 0, stream>>>(scores, toks_all, maps_all, out);
}

// Round 4
// 53283.435 us; speedup vs baseline: 1.9731x; 1.4195x over previous
//
#include <hip/hip_runtime.h>
#include <cmath>
#include <cfloat>

#define Hdim 768
#define Bb 32
#define Kb 5
#define Ss 64
#define Vv 30522
#define Tt 40
#define SEPTOK 102

// ---------------------------------------------------------------------------
// fp64-accumulate GEMM, LDS-staged X, 2 cols/thread:
//   out[n,i] = f32( sum_p (double)X[n*xrs+p] * (double)W[p*sWp + i*sWi] ) (+bias f32)
// Block: 256 threads -> 512 output cols x NT rows. P multiple of 256,
// N multiple of NT. X staged as doubles in LDS (exact f32->f64), broadcast
// reads. W coalesced when sWi==1 (pre-transposed weights).
// ---------------------------------------------------------------------------
template<int NT>
__global__ __launch_bounds__(256) void gemmT_k(int N, int P, int I, int xrs,
    long long sWp, long long sWi,
    const float* __restrict__ Xf, const float* __restrict__ W,
    const float* __restrict__ bias, float* __restrict__ out)
{
    __shared__ double xs[NT][256];
    int tid = threadIdx.x;
    int i0 = blockIdx.x * 512 + tid;         // col A
    int i1 = i0 + 256;                       // col B
    int n0 = blockIdx.y * NT;
    long long i0c = (i0 < I) ? i0 : (I - 1); // clamp loads, keep flow uniform
    long long i1c = (i1 < I) ? i1 : (I - 1);
    double acc0[NT], acc1[NT];
#pragma unroll
    for (int r = 0; r < NT; r++) { acc0[r] = 0.0; acc1[r] = 0.0; }
    int nch = P >> 8;
    for (int c = 0; c < nch; c++) {
        __syncthreads();
        for (int idx = tid; idx < NT * 256; idx += 256) {
            int r = idx >> 8, p = idx & 255;
            xs[r][p] = (double)Xf[(size_t)(n0 + r) * xrs + c * 256 + p];
        }
        __syncthreads();
        const float* wrow = W + (size_t)c * 256 * sWp;
#pragma unroll 2
        for (int p = 0; p < 256; p++) {
            double w0 = (double)wrow[(size_t)p * sWp + i0c * sWi];
            double w1 = (double)wrow[(size_t)p * sWp + i1c * sWi];
#pragma unroll
            for (int r = 0; r < NT; r++) {
                double x = xs[r][p];
                acc0[r] = ::fma(x, w0, acc0[r]);
                acc1[r] = ::fma(x, w1, acc1[r]);
            }
        }
    }
    if (i0 < I) {
#pragma unroll
        for (int r = 0; r < NT; r++) {
            float s = (float)acc0[r];
            if (bias) s = __fadd_rn(s, bias[i0]);
            out[(size_t)(n0 + r) * I + i0] = s;
        }
    }
    if (i1 < I) {
#pragma unroll
        for (int r = 0; r < NT; r++) {
            float s = (float)acc1[r];
            if (bias) s = __fadd_rn(s, bias[i1]);
            out[(size_t)(n0 + r) * I + i1] = s;
        }
    }
}

// tiled transpose: out[c*R + r] = in[r*C + c]
__global__ __launch_bounds__(256) void transpose_tiled_k(
    const float* __restrict__ in, float* __restrict__ out, int R, int C)
{
    __shared__ float tile[32][33];
    int c0 = blockIdx.x * 32, r0 = blockIdx.y * 32;
    int tx = threadIdx.x & 31, ty = threadIdx.x >> 5;   // ty in [0,8)
    for (int dy = 0; dy < 32; dy += 8) {
        int r = r0 + ty + dy, c = c0 + tx;
        if (r < R && c < C) tile[ty + dy][tx] = in[(size_t)r * C + c];
    }
    __syncthreads();
    for (int dy = 0; dy < 32; dy += 8) {
        int r = r0 + tx, c = c0 + ty + dy;
        if (r < R && c < C) out[(size_t)c * R + r] = tile[tx][ty + dy];
    }
}

// gather parent hidden + token embedding (all f32)
__global__ __launch_bounds__(256) void gather_k(int N, int Kcur,
    const int* __restrict__ maps, const int* __restrict__ toks,
    const float* __restrict__ h_beam, const float* __restrict__ E,
    float* __restrict__ h_g, float* __restrict__ xbuf)
{
    int n = blockIdx.x;
    if (n >= N) return;
    int b = n / Kcur;
    int tok = toks ? toks[n] : SEPTOK;
    const float* er = E + (size_t)tok * Hdim;
    if (maps) {
        const float* hs = h_beam + (size_t)(b * Kb + maps[n]) * Hdim;
        for (int j = threadIdx.x; j < Hdim; j += 256) {
            h_g[(size_t)n * Hdim + j]  = hs[j];
            xbuf[(size_t)n * 1536 + j] = er[j];
        }
    } else {  // step 0: zero hidden
        for (int j = threadIdx.x; j < Hdim; j += 256) {
            h_g[(size_t)n * Hdim + j]  = 0.f;
            xbuf[(size_t)n * 1536 + j] = er[j];
        }
    }
}

// step-0 broadcast: h_beam[b,k,:] = h_tmp[b,:]
__global__ __launch_bounds__(256) void bcast_k(const float* __restrict__ h_tmp,
                                               float* __restrict__ h_beam)
{
    int b = blockIdx.x;
    for (int j = threadIdx.x; j < Hdim; j += 256) {
        float v = h_tmp[(size_t)b * Hdim + j];
        for (int k = 0; k < Kb; k++)
            h_beam[(size_t)(b * Kb + k) * Hdim + j] = v;
    }
}

// attention: e = tanh(srcWa + hUa) @ va; softmax over S; ctx -> xbuf[768:]
__global__ __launch_bounds__(256) void attn2_k(int N, int Kcur,
    const float* __restrict__ hUa, const float* __restrict__ srcWa,
    const float* __restrict__ src, const float* __restrict__ va,
    float* __restrict__ xbuf)
{
    __shared__ float hu[Hdim];
    __shared__ float va_s[Hdim];
    __shared__ float e_s[Ss];
    __shared__ float a_s[Ss];
    int n = blockIdx.x, tid = threadIdx.x;
    if (n >= N) return;
    int b = n / Kcur;
    for (int j = tid; j < Hdim; j += 256) {
        hu[j]   = hUa[(size_t)n * Hdim + j];
        va_s[j] = va[j];
    }
    __syncthreads();
    int wv = tid >> 6, ln = tid & 63;
    for (int s = wv * 16; s < wv * 16 + 16; s++) {
        const float* sw = srcWa + (size_t)(b * Ss + s) * Hdim;
        double p = 0.0;
        for (int j = ln; j < Hdim; j += 64) {
            float tv = (float)tanh((double)__fadd_rn(sw[j], hu[j]));  // f32 add, true tanh
            p = ::fma((double)tv, (double)va_s[j], p);
        }
        for (int off = 32; off; off >>= 1) p += __shfl_down(p, off, 64);
        if (ln == 0) e_s[s] = (float)p;
    }
    __syncthreads();
    if (tid < 64) {
        float v = e_s[tid], m = v;
        for (int off = 32; off; off >>= 1) m = fmaxf(m, __shfl_xor(m, off, 64));
        float p = (float)exp((double)__fsub_rn(v, m));
        double sum = (double)p;
        for (int off = 32; off; off >>= 1) sum += __shfl_xor(sum, off, 64);
        a_s[tid] = __fdiv_rn(p, (float)sum);
    }
    __syncthreads();
    for (int j = tid; j < Hdim; j += 256) {
        double acc = 0.0;
        for (int s = 0; s < Ss; s++)
            acc = ::fma((double)a_s[s], (double)src[(size_t)(b * Ss + s) * Hdim + j], acc);
        xbuf[(size_t)n * 1536 + 768 + j] = (float)acc;  // round to f32 (ref x is f32)
    }
}

// GRU gates; transcendentals in double rounded to f32, f32 combine chain as ref
__global__ __launch_bounds__(256) void gate_k(int N,
    const float* __restrict__ gx, const float* __restrict__ gh,
    const float* __restrict__ h_g, float* __restrict__ h_out)
{
    int idx = blockIdx.x * 256 + threadIdx.x;
    if (idx >= N * Hdim) return;
    int n = idx / Hdim, i = idx - n * Hdim;
    const float* gxr = gx + (size_t)n * 2304;
    const float* ghr = gh + (size_t)n * 2304;
    float xr = gxr[i], xz = gxr[768 + i], xn = gxr[1536 + i];
    float hr = ghr[i], hz = ghr[768 + i], hn = ghr[1536 + i];
    float r  = (float)(1.0 / (1.0 + exp(-(double)__fadd_rn(xr, hr))));
    float z  = (float)(1.0 / (1.0 + exp(-(double)__fadd_rn(xz, hz))));
    float nn = (float)tanh((double)__fadd_rn(xn, __fmul_rn(r, hn)));
    float hv = h_g[(size_t)n * Hdim + i];
    float h2 = __fadd_rn(__fmul_rn(__fsub_rn(1.f, z), nn), __fmul_rn(z, hv));
    h_out[(size_t)n * Hdim + i] = h2;
}

// per-row max and l = f32(log(f32(sum of f32-rounded exp)))
__global__ __launch_bounds__(256) void lse_k(int N,
    const float* __restrict__ logits, float* __restrict__ mx, float* __restrict__ lgs)
{
    __shared__ float  redf[256];
    __shared__ double redd[256];
    int n = blockIdx.x, tid = threadIdx.x;
    const float* lg = logits + (size_t)n * Vv;
    float m = -INFINITY;
    for (int v = tid; v < Vv; v += 256) m = fmaxf(m, lg[v]);
    redf[tid] = m; __syncthreads();
    for (int off = 128; off; off >>= 1) {
        if (tid < off) redf[tid] = fmaxf(redf[tid], redf[tid + off]);
        __syncthreads();
    }
    m = redf[0];
    double s = 0.0;
    for (int v = tid; v < Vv; v += 256) {
        float ex = (float)exp((double)__fsub_rn(lg[v], m));
        s += (double)ex;
    }
    redd[tid] = s; __syncthreads();
    for (int off = 128; off; off >>= 1) {
        if (tid < off) redd[tid] += redd[tid + off];
        __syncthreads();
    }
    if (tid == 0) {
        mx[n] = m;
        float sf = (float)redd[0];
        lgs[n] = (float)log((double)sf);
    }
}

// ------------------------- top-k helpers -----------------------------------
__device__ __forceinline__ bool betterf(float va, int ja, float vb, int jb) {
    return (va > vb) || (va == vb && ja < jb);  // jax tie-break: lower index
}
__device__ __forceinline__ void ins5(float* tv, int* tj, float v, int j) {
    if (!betterf(v, j, tv[4], tj[4])) return;
    tv[4] = v; tj[4] = j;
#pragma unroll
    for (int q = 4; q > 0; q--) {
        if (betterf(tv[q], tj[q], tv[q - 1], tj[q - 1])) {
            float t = tv[q]; tv[q] = tv[q - 1]; tv[q - 1] = t;
            int  ti = tj[q]; tj[q] = tj[q - 1]; tj[q - 1] = ti;
        }
    }
}

// single scan with per-thread top-5, then 5-pass argmax over the LDS pool
__global__ __launch_bounds__(256) void topk5_k(int t,
    const float* __restrict__ logits, const float* __restrict__ mx, const float* __restrict__ lgs,
    float* scores, float* ended, float* lengths,
    int* toks_cur, int* maps_cur, int* toks_all, int* maps_all)
{
    __shared__ float sc_s[Kb], den_s[Kb], end_s[Kb], len_s[Kb], mx_s[Kb], lg_s[Kb];
    __shared__ float mv[256 * 5];
    __shared__ int   mj[256 * 5];
    __shared__ float rv[256];
    __shared__ int   rj[256];
    __shared__ int   selj[Kb];
    int b = blockIdx.x, tid = threadIdx.x;
    int Kcur = (t == 0) ? 1 : Kb;
    if (tid < Kb) {
        if (t == 0) {
            sc_s[tid] = 0.f; end_s[tid] = 0.f; len_s[tid] = 0.f; den_s[tid] = 1.f;
            mx_s[tid] = mx[b]; lg_s[tid] = lgs[b];
        } else {
            float e0 = ended[b * Kb + tid];
            float ln = __fadd_rn(lengths[b * Kb + tid], (e0 == 0.f) ? 1.f : 0.f);
            sc_s[tid]  = scores[b * Kb + tid];
            end_s[tid] = e0;
            len_s[tid] = ln;
            den_s[tid] = (tid < Kb - 1) ? (float)pow((double)ln, (double)0.7f) : 1.f;
            mx_s[tid]  = mx[b * Kb + tid];
            lg_s[tid]  = lgs[b * Kb + tid];
        }
    }
    __syncthreads();
    const float* lbase = logits + (size_t)b * Kcur * Vv;
    float tv[5]; int tj[5];
#pragma unroll
    for (int q = 0; q < 5; q++) { tv[q] = -INFINITY; tj[q] = 0x7fffffff; }
    for (int k = 0; k < Kcur; k++) {
        if (end_s[k] == 0.f) {
            float m = mx_s[k], l = lg_s[k], sck = sc_s[k], den = den_s[k];
            const float* lg = lbase + (size_t)k * Vv;
            for (int v = tid; v < Vv; v += 256) {
                float lp  = __fsub_rn(__fsub_rn(lg[v], m), l);
                float val = __fdiv_rn(__fadd_rn(lp, sck), den);
                ins5(tv, tj, val, k * Vv + v);
            }
        } else if (tid == 0) {
            // lp at SEP is 0: val = fdiv(fadd(0, sc), den) == fdiv(sc, den)
            float val = __fdiv_rn(sc_s[k], den_s[k]);
            ins5(tv, tj, val, k * Vv + SEPTOK);
        }
    }
#pragma unroll
    for (int q = 0; q < 5; q++) { mv[tid * 5 + q] = tv[q]; mj[tid * 5 + q] = tj[q]; }
    __syncthreads();
    for (int pass = 0; pass < Kb; pass++) {
        float bv = -INFINITY; int bj = 0x7fffffff;
#pragma unroll
        for (int q = 0; q < 5; q++) {
            float v = mv[tid * 5 + q]; int j = mj[tid * 5 + q];
            if (betterf(v, j, bv, bj)) { bv = v; bj = j; }
        }
        rv[tid] = bv; rj[tid] = bj;
        __syncthreads();
        for (int off = 128; off; off >>= 1) {
            if (tid < off) {
                float ov = rv[tid + off]; int oj = rj[tid + off];
                if (betterf(ov, oj, rv[tid], rj[tid])) { rv[tid] = ov; rj[tid] = oj; }
            }
            __syncthreads();
        }
        if (tid == 0) selj[pass] = rj[0];
        __syncthreads();
#pragma unroll
        for (int q = 0; q < 5; q++)                      // invalidate selected (j unique)
            if (mj[tid * 5 + q] == selj[pass]) { mv[tid * 5 + q] = -INFINITY; mj[tid * 5 + q] = 0x7fffffff; }
        __syncthreads();
    }
    if (tid == 0) {
        for (int q = 0; q < Kb; q++) {
            int jj = selj[q];
            int pk = jj / Vv, vv = jj - pk * Vv;
            float lp;
            if (end_s[pk] == 0.f)
                lp = __fsub_rn(__fsub_rn(lbase[(size_t)pk * Vv + vv], mx_s[pk]), lg_s[pk]);
            else
                lp = (vv == SEPTOK) ? 0.f : -1e9f;
            float cand = __fadd_rn(lp, sc_s[pk]);        // unnormalized, as ref carries
            scores[b * Kb + q]   = cand;
            toks_cur[b * Kb + q] = vv;
            maps_cur[b * Kb + q] = (t == 0) ? 0 : pk;
            if (t == 0) {
                ended[b * Kb + q]   = 0.f;
                lengths[b * Kb + q] = 0.f;
            } else {
                // reference quirk: ended/lengths indexed by NEW slot, OLD meaning
                ended[b * Kb + q]   = (vv == SEPTOK) ? 1.f : end_s[q];
                lengths[b * Kb + q] = len_s[q];
            }
            toks_all[(size_t)t * Bb * Kb + b * Kb + q] = vv;
            maps_all[(size_t)t * Bb * Kb + b * Kb + q] = (t == 0) ? 0 : pk;
        }
    }
}

__global__ void back_k(const float* __restrict__ scores,
                       const int* __restrict__ toks_all, const int* __restrict__ maps_all,
                       int* __restrict__ out)
{
    int b = threadIdx.x;
    if (b >= Bb) return;
    int best = 0; float bvv = scores[b * Kb];
    for (int k = 1; k < Kb; k++) {
        float v = scores[b * Kb + k];
        if (v > bvv) { bvv = v; best = k; }  // strict > = first-occurrence argmax
    }
    int cur = best;
    for (int t = Tt - 1; t >= 0; t--) {
        out[b * Tt + t] = toks_all[t * Bb * Kb + b * Kb + cur];
        cur = maps_all[t * Bb * Kb + b * Kb + cur];
    }
}

// ---------------------------------------------------------------------------
extern "C" void kernel_launch(void* const* d_in, const int* in_sizes, int n_in,
                              void* d_out, int out_size, void* d_ws, size_t ws_size,
                              hipStream_t stream)
{
    const float* src  = (const float*)d_in[0];
    const float* E    = (const float*)d_in[1];
    const float* Wa   = (const float*)d_in[2];
    const float* Ua   = (const float*)d_in[3];
    const float* va   = (const float*)d_in[4];
    const float* W_ih = (const float*)d_in[5];
    const float* W_hh = (const float*)d_in[6];
    const float* b_ih = (const float*)d_in[7];
    const float* b_hh = (const float*)d_in[8];
    const float* Wo   = (const float*)d_in[9];
    const float* bo   = (const float*)d_in[10];
    int* out = (int*)d_out;

    // workspace bump allocator
    char* w = (char*)d_ws;
    size_t used = 0;
    auto alloc = [&](size_t bytes) -> char* {
        char* p = w + used;
        used += (bytes + 255) & ~(size_t)255;
        return p;
    };
    float*  srcWa   = (float*) alloc((size_t)Bb * Ss * Hdim * 4);
    float*  h_beam  = (float*) alloc((size_t)Bb * Kb * Hdim * 4);
    float*  h_tmp   = (float*) alloc((size_t)Bb * Hdim * 4);
    float*  h_g     = (float*) alloc((size_t)Bb * Kb * Hdim * 4);
    float*  hUa     = (float*) alloc((size_t)Bb * Kb * Hdim * 4);
    float*  xbuf    = (float*) alloc((size_t)Bb * Kb * 1536 * 4);
    float*  gx      = (float*) alloc((size_t)Bb * Kb * 2304 * 4);
    float*  gh      = (float*) alloc((size_t)Bb * Kb * 2304 * 4);
    float*  logits  = (float*) alloc((size_t)Bb * Kb * Vv * 4);
    float*  mx      = (float*) alloc(Bb * Kb * 4);
    float*  lgs     = (float*) alloc(Bb * Kb * 4);
    float*  scores  = (float*) alloc(Bb * Kb * 4);
    float*  ended   = (float*) alloc(Bb * Kb * 4);
    float*  lengths = (float*) alloc(Bb * Kb * 4);
    int* toks_cur = (int*)alloc(Bb * Kb * 4);
    int* maps_cur = (int*)alloc(Bb * Kb * 4);
    int* toks_all = (int*)alloc((size_t)Tt * Bb * Kb * 4);
    int* maps_all = (int*)alloc((size_t)Tt * Bb * Kb * 4);

    // layered fallback for weight transposes (coalesced W reads)
    size_t sz_ihT = (size_t)2304 * 1536 * 4;
    size_t sz_hhT = (size_t)2304 * Hdim * 4;
    size_t sz_woT = (size_t)Vv * Hdim * 4;
    float* wihT = nullptr; float* whhT = nullptr; float* woT = nullptr;
    if (ws_size >= used + sz_ihT + sz_hhT + 512) {
        wihT = (float*)alloc(sz_ihT);
        whhT = (float*)alloc(sz_hhT);
    }
    if (ws_size >= used + sz_woT + 512) {
        woT = (float*)alloc(sz_woT);
    }

    // ---------------- one-time init (inside capture; deterministic) --------
    if (wihT) {
        transpose_tiled_k<<<dim3((1536 + 31) / 32, (2304 + 31) / 32), 256, 0, stream>>>(W_ih, wihT, 2304, 1536);
        transpose_tiled_k<<<dim3((Hdim + 31) / 32, (2304 + 31) / 32), 256, 0, stream>>>(W_hh, whhT, 2304, Hdim);
    }
    if (woT)
        transpose_tiled_k<<<dim3((Hdim + 31) / 32, (Vv + 31) / 32), 256, 0, stream>>>(Wo, woT, Vv, Hdim);

    // srcWa = src @ Wa : Wa[p][i] row-major -> sWp=768, sWi=1 (coalesced)
    gemmT_k<16><<<dim3(2, (Bb * Ss) / 16), 256, 0, stream>>>(
        Bb * Ss, Hdim, Hdim, Hdim, (long long)Hdim, 1LL, src, Wa, nullptr, srcWa);

    // weight access descriptors: {ptr, sWp, sWi}
    const float* Wih_p = wihT ? wihT : W_ih;
    long long    Wih_sp = wihT ? 2304LL : 1LL, Wih_si = wihT ? 1LL : 1536LL;
    const float* Whh_p = whhT ? whhT : W_hh;
    long long    Whh_sp = whhT ? 2304LL : 1LL, Whh_si = whhT ? 1LL : (long long)Hdim;
    const float* Wo_p  = woT ? woT : Wo;
    long long    Wo_sp = woT ? (long long)Vv : 1LL, Wo_si = woT ? 1LL : (long long)Hdim;

    for (int t = 0; t < Tt; t++) {
        int N  = (t == 0) ? Bb : Bb * Kb;
        int Kc = (t == 0) ? 1 : Kb;
        const int* mp = (t == 0) ? nullptr : maps_cur;
        const int* tk = (t == 0) ? nullptr : toks_cur;
        float* h_cur = (t == 0) ? h_tmp : h_beam;

        gather_k<<<N, 256, 0, stream>>>(N, Kc, mp, tk, h_beam, E, h_g, xbuf);
        // h @ Ua : Ua[p][i] -> sWp=768, sWi=1
        gemmT_k<4><<<dim3(2, N / 4), 256, 0, stream>>>(
            N, Hdim, Hdim, Hdim, (long long)Hdim, 1LL, h_g, Ua, nullptr, hUa);
        attn2_k<<<N, 256, 0, stream>>>(N, Kc, hUa, srcWa, src, va, xbuf);
        // x @ W_ih.T
        gemmT_k<4><<<dim3(5, N / 4), 256, 0, stream>>>(
            N, 1536, 2304, 1536, Wih_sp, Wih_si, xbuf, Wih_p, b_ih, gx);
        // h @ W_hh.T
        gemmT_k<4><<<dim3(5, N / 4), 256, 0, stream>>>(
            N, Hdim, 2304, Hdim, Whh_sp, Whh_si, h_g, Whh_p, b_hh, gh);
        gate_k<<<(N * Hdim + 255) / 256, 256, 0, stream>>>(N, gx, gh, h_g, h_cur);
        if (t == 0)
            bcast_k<<<Bb, 256, 0, stream>>>(h_tmp, h_beam);
        // h2 @ Wo.T  (the big one): 60 col-blocks x N/16 row-blocks
        gemmT_k<16><<<dim3(60, N / 16), 256, 0, stream>>>(
            N, Hdim, Vv, Hdim, Wo_sp, Wo_si, h_cur, Wo_p, bo, logits);
        lse_k<<<N, 256, 0, stream>>>(N, logits, mx, lgs);
        topk5_k<<<Bb, 256, 0, stream>>>(t, logits, mx, lgs, scores, ended, lengths,
                                        toks_cur, maps_cur, toks_all, maps_all);
    }
    back_k<<<1, 64, 0, stream>>>(scores, toks_all, maps_all, out);
}